// Round 3
// baseline (528.513 us; speedup 1.0000x reference)
//
#include <hip/hip_runtime.h>

// SegZeroPadding: x [B=64, L=1000, D=128] fp32 -> out [B, 16000, D] fp32.
// seg_num=4 (hardcoded per setup_inputs). Segment stride = seg_len*L = 4000
// rows; segment s occupies rows [s*4000, s*4000+1000). Non-overlapping ->
// scatter-add == placement.
//
// R3 restructure: ONE store per thread, blocks walk the output buffer
// LINEARLY — byte-identical access pattern to the rocclr fill kernel that
// demonstrably sustains 6.28 TB/s on this very buffer in this very graph.
// Rationale: R0 (NT stores) vs R2 (plain stores) were identical (~188 us
// non-fill time vs ~89 us roofline), exonerating the store type; the prior
// structure's 4 scattered store streams per thread (2.048 MB apart, ~8192
// concurrent 4 KB write fronts chip-wide) is the remaining suspect for the
// ~2x write-throughput deficit.
// Trade: x rows are read 4x (once per segment) instead of 1x, but x is
// 33.5 MB — fully L3-resident — so HBM read traffic stays ~33 MB and the
// re-reads hit L2/L3. Loads are PLAIN (cached) now: we want x cached.

#define B_       64
#define L_       1000
#define D4_      32            // float4 per row (D=128 floats)
#define XLEN_    16000
#define SEGSTR_  4000          // seg_len * L

typedef float v4f __attribute__((ext_vector_type(4)));

__global__ __launch_bounds__(256) void seg_zero_pad_kernel(
        const v4f* __restrict__ x, v4f* __restrict__ out) {
    // One thread per output float4 within one batch slice.
    // Per b: 16000 rows x 32 float4 = 512,000 threads = 2000 blocks.
    const int t     = blockIdx.x * blockDim.x + threadIdx.x; // 0 .. 511999
    const int b     = blockIdx.z;
    const int d4    = t & (D4_ - 1);
    const int row16 = t >> 5;                                // 0 .. 15999

    // r = row16 % 4000 (compiler lowers const-div to magic-mul; cheap).
    const int seg = row16 / SEGSTR_;
    const int r   = row16 - seg * SEGSTR_;                   // 0 .. 3999

    v4f v = (v4f)(0.f);
    if (r < L_) {
        v = x[(size_t)(b * L_ + r) * D4_ + d4];              // cached load
    }

    // Single, perfectly linear store front (fill-kernel pattern).
    out[((size_t)b * XLEN_ + row16) * D4_ + d4] = v;
}

extern "C" void kernel_launch(void* const* d_in, const int* in_sizes, int n_in,
                              void* d_out, int out_size, void* d_ws, size_t ws_size,
                              hipStream_t stream) {
    const v4f* x = (const v4f*)d_in[0];
    v4f* out = (v4f*)d_out;

    dim3 block(256, 1, 1);
    dim3 grid((XLEN_ * D4_) / 256, 1, B_);  // 2000 x 1 x 64
    seg_zero_pad_kernel<<<grid, block, 0, stream>>>(x, out);
}